// Round 4
// baseline (193.397 us; speedup 1.0000x reference)
//
#include <hip/hip_runtime.h>

// SdfParseLoss: scatter-min/max of sdf over pixel grid, then masked mean loss.
// H=256, W=192, B=64, V=100000. Output: 64 floats.
//
// Round 4: S=8 pixel slices (30KB LDS -> 2 blocks/CU, 32 waves/CU) + XCD-aware
// block swizzle so all 8 slice-blocks of one batch land on the SAME XCD and
// share its L2 for the replicated vertex stream (1.2MB/batch << 4MB L2).
// Per-pixel only min (gt==1) or max (gt==0) is consumed -> single LDS
// atomicMin with key inversion for neg pixels. Empty pixels contribute 0.

#define HH 256
#define WW 192
#define HW (HH * WW)
#define NB 64
#define NV 100000
#define S 8
#define RANGE (HW / S)          // 6144 pixels per block (32 rows)
#define EMPTY_KEY 0xFFFFFFFFu

// Order-preserving float <-> uint transform so unsigned min gives float min.
__device__ __forceinline__ unsigned fkey(float f) {
    unsigned u = __float_as_uint(f);
    return (u & 0x80000000u) ? ~u : (u | 0x80000000u);
}
__device__ __forceinline__ float funkey(unsigned k) {
    unsigned u = (k & 0x80000000u) ? (k ^ 0x80000000u) : ~k;
    return __uint_as_float(u);
}

__global__ __launch_bounds__(1024) void fused_kernel(
        const float* __restrict__ sdf,
        const float* __restrict__ mesh,     // [B,V,2] interleaved
        const int* __restrict__ gt,
        const float* __restrict__ thr_p,
        float* __restrict__ sums,
        unsigned* __restrict__ counts) {
    __shared__ unsigned ldsk[RANGE];        // 24 KB
    __shared__ unsigned char gtb[RANGE];    //  6 KB
    // XCD swizzle: consecutive blockIdx round-robin over 8 XCDs. Map so the
    // 8 slice-blocks of batch b all have the same (blockIdx & 7) -> same XCD.
    const int lin  = blockIdx.x;            // 0..511
    const int xcd  = lin & 7;
    const int slot = lin >> 3;              // 0..63
    const int b    = xcd * 8 + (slot >> 3); // 8 batches per XCD
    const int q    = slot & 7;
    const int p0   = q * RANGE;
    const int tid  = threadIdx.x;

    // init keys + stage gt slice into LDS; track pos-pixel existence
    int lpos = 0;
    const int* gtbase = gt + b * HW + p0;
    for (int j = tid; j < RANGE; j += 1024) {
        ldsk[j] = EMPTY_KEY;
        int g = gtbase[j];
        gtb[j] = (unsigned char)g;
        lpos |= (g == 1);
    }
    __syncthreads();

    // stream the batch's vertices: 4 verts per thread-iteration
    const float4* sdf4 = (const float4*)(sdf + (size_t)b * NV);
    const float4* m4   = (const float4*)(mesh + (size_t)b * NV * 2);
    const float thr = thr_p[0];
    for (int g = tid; g < NV / 4; g += 1024) {
        float4 s4 = sdf4[g];
        float4 ma = m4[2 * g];
        float4 mb = m4[2 * g + 1];
        float xs[4] = {ma.x, ma.z, mb.x, mb.z};
        float ys[4] = {ma.y, ma.w, mb.y, mb.w};
        float ss[4] = {s4.x, s4.y, s4.z, s4.w};
        #pragma unroll
        for (int j = 0; j < 4; ++j) {
            int x = (int)xs[j];   // trunc toward zero == jnp astype(int32)
            int y = (int)ys[j];
            if ((unsigned)x < WW && (unsigned)y < HH) {
                int p = y * WW + x - p0;
                if ((unsigned)p < RANGE) {
                    unsigned k = fkey(ss[j]);
                    if (gtb[p] == 0) k = ~k;   // neg pixel: min of ~k == max
                    atomicMin(&ldsk[p], k);
                }
            }
        }
    }
    __syncthreads();

    // partial loss over this slice (empty pixels contribute exactly 0)
    float lsum = 0.f;
    for (int j = tid; j < RANGE; j += 1024) {
        unsigned k = ldsk[j];
        if (k != EMPTY_KEY)
            lsum += gtb[j] ? fabsf(funkey(k)) : fabsf(funkey(~k) - thr);
    }
    #pragma unroll
    for (int off = 32; off > 0; off >>= 1)
        lsum += __shfl_down(lsum, off, 64);
    unsigned long long m = __ballot(lpos != 0);
    if ((tid & 63) == 0) {
        atomicAdd(&sums[b], lsum);
        if (m) atomicOr(&counts[b], 1u);
    }
}

__global__ void final_kernel(const float* __restrict__ sums,
                             const unsigned* __restrict__ counts,
                             const float* __restrict__ pv,
                             float* __restrict__ out) {
    int b = threadIdx.x;
    if (b < NB) {
        float s = sums[b] * (1.0f / HW) * pv[b];
        out[b] = counts[b] ? s : 0.0f;
    }
}

extern "C" void kernel_launch(void* const* d_in, const int* in_sizes, int n_in,
                              void* d_out, int out_size, void* d_ws, size_t ws_size,
                              hipStream_t stream) {
    const float* sdf  = (const float*)d_in[0];
    const float* mesh = (const float*)d_in[1];
    const int*   gt   = (const int*)d_in[2];
    const float* thr  = (const float*)d_in[3];
    const float* pv   = (const float*)d_in[5];   // parse_valid [B,1,1]
    float* out = (float*)d_out;

    float*    sums   = (float*)d_ws;
    unsigned* counts = (unsigned*)((char*)d_ws + NB * 4);

    // ws is poisoned 0xAA before every call: zero sums+counts (contiguous)
    hipMemsetAsync(sums, 0, NB * 4 * 2, stream);

    fused_kernel<<<NB * S, 1024, 0, stream>>>(sdf, mesh, gt, thr, sums, counts);

    final_kernel<<<1, 64, 0, stream>>>(sums, counts, pv, out);
}